// Round 11
// baseline (156.600 us; speedup 1.0000x reference)
//
#include <hip/hip_runtime.h>
#include <hip/hip_bf16.h>

// Problem constants (BertMultiPooler: B=32, S=4096, H=768, K=64)
#define NB 32
#define NS 4096
#define NH 768
#define NK 64
#define NM (NB * NK)   // 2048 output rows
#define ND (2 * NH)    // 1536 GEMM reduction dim
#define KT_TILES (ND / 64)   // 24 GEMM K-tiles of 64 (BK=64 gemm)

// pool geometry: uniform 64-row chunks
#define CSHIFT 6
#define CROWS 64                 // rows per chunk
#define BPB (NS / CROWS)         // 64 chunks per batch
#define PBLOCKS (NB * BPB)       // 2048 pool blocks
#define NSLOT (BPB + 1)          // 65 partial slots per segment
#define WCONV_BLOCKS 384         // appended blocks for weight convert

typedef short short8 __attribute__((ext_vector_type(8)));
typedef float floatx4 __attribute__((ext_vector_type(4)));

__device__ __forceinline__ unsigned short f2bf(float f) {
    union { float f; unsigned u; } v; v.f = f;
    unsigned r = v.u + 0x7FFFu + ((v.u >> 16) & 1u);   // RNE to bf16
    return (unsigned short)(r >> 16);
}

#define ACC4(s, p) { s.x += p.x; s.y += p.y; s.z += p.z; s.w += p.w; }

// ---------------------------------------------------------------------------
// Kernel A: uniform-chunk segment partial sums + fused weight convert.
// (R8 structure verbatim — regular cached loads; A/B isolates R10's NT lever.)
// Blocks [0,2048): one 64-row chunk (192 KB contiguous, uniform) per block.
// 192 threads; thread t owns cols 4t..4t+3. 8-deep register ping-pong.
// Per segment-run inside the chunk, flush one dense f32 partial slot:
//   partials[(seg*NSLOT + (chunk - seg_start_chunk))*NH + col]
// Blocks [2048, 2432): bf16 weight convert Wc = [W_dense | W_tab] rows.
// ---------------------------------------------------------------------------
__global__ __launch_bounds__(192) void pool_chunk_kernel(const float* __restrict__ hs,
                                                         const int* __restrict__ cls,
                                                         const int* __restrict__ tlen,
                                                         float* __restrict__ partials,
                                                         const float* __restrict__ Wd,
                                                         const float* __restrict__ Wt,
                                                         unsigned short* __restrict__ Wc) {
    const int bi = blockIdx.x;
    const int t  = threadIdx.x;          // 0..191

    if (bi >= PBLOCKS) {                 // ---- wconv part ----
        const int wb = bi - PBLOCKS;     // 0..383
        #pragma unroll
        for (int j = 0; j < 4; ++j) {
            int i = wb * 768 + j * 192 + t;      // float4 index, < NH*ND/4
            int e = i * 4;
            int n = e / ND;
            int k = e % ND;
            float4 v = (k < NH) ? *(const float4*)&Wd[n * NH + k]
                                : *(const float4*)&Wt[n * NH + (k - NH)];
            ushort4 o;
            o.x = f2bf(v.x); o.y = f2bf(v.y); o.z = f2bf(v.z); o.w = f2bf(v.w);
            *(ushort4*)&Wc[e] = o;
        }
        return;
    }

    // ---- pooling chunk ----
    const int b  = bi >> CSHIFT;         // batch (64 chunks per batch)
    const int ck = bi & (BPB - 1);       // chunk index within batch
    const int r0 = ck << CSHIFT;
    const int tl = tlen[b];
    int r_end = r0 + CROWS;
    if (r_end > tl) r_end = tl;
    if (r0 >= r_end) return;

    // s = upper_bound(pos, r0) - 1 over pos[k] = cls[((b<<6)+k)*2+1]
    int lo = 0, hb = NK;
    while (lo < hb) {
        int mid = (lo + hb) >> 1;
        int p = cls[(((b << 6) + mid) << 1) + 1];
        if (p <= r0) lo = mid + 1; else hb = mid;
    }
    int s = lo - 1;
    int r = r0;
    if (s < 0) {                         // rows before first boundary: invalid
        int p0 = cls[((b << 6) << 1) + 1];
        r = (p0 < r_end) ? p0 : r_end;
        s = 0;
        if (r >= r_end) return;
    }

    const float4* base = (const float4*)(hs + (size_t)b * NS * NH) + t;

    while (r < r_end) {
        int nb = r_end;
        if (s + 1 < NK) {
            int p = cls[(((b << 6) + s + 1) << 1) + 1];
            if (p < nb) nb = p;
        }
        const int n = nb - r;
        const float4* p4 = base + (size_t)r * (NH / 4);

        float4 s0 = {0,0,0,0}, s1 = {0,0,0,0}, s2 = {0,0,0,0}, s3 = {0,0,0,0};
        int i = 0;
        if (n >= 8) {
            float4 p0 = p4[0*(NH/4)], p1 = p4[1*(NH/4)], p2 = p4[2*(NH/4)], p3 = p4[3*(NH/4)];
            float4 a4 = p4[4*(NH/4)], a5 = p4[5*(NH/4)], a6 = p4[6*(NH/4)], a7 = p4[7*(NH/4)];
            for (i = 8; i + 8 <= n; i += 8) {
                float4 q0 = p4[(size_t)(i+0) * (NH/4)];
                float4 q1 = p4[(size_t)(i+1) * (NH/4)];
                float4 q2 = p4[(size_t)(i+2) * (NH/4)];
                float4 q3 = p4[(size_t)(i+3) * (NH/4)];
                float4 q4 = p4[(size_t)(i+4) * (NH/4)];
                float4 q5 = p4[(size_t)(i+5) * (NH/4)];
                float4 q6 = p4[(size_t)(i+6) * (NH/4)];
                float4 q7 = p4[(size_t)(i+7) * (NH/4)];
                ACC4(s0, p0) ACC4(s1, p1) ACC4(s2, p2) ACC4(s3, p3)
                ACC4(s0, a4) ACC4(s1, a5) ACC4(s2, a6) ACC4(s3, a7)
                p0 = q0; p1 = q1; p2 = q2; p3 = q3;
                a4 = q4; a5 = q5; a6 = q6; a7 = q7;
            }
            ACC4(s0, p0) ACC4(s1, p1) ACC4(s2, p2) ACC4(s3, p3)
            ACC4(s0, a4) ACC4(s1, a5) ACC4(s2, a6) ACC4(s3, a7)
        }
        for (; i < n; ++i) {
            float4 v = p4[(size_t)i * (NH/4)];
            ACC4(s0, v)
        }
        ACC4(s0, s1) ACC4(s2, s3) ACC4(s0, s2)

        const int start_s = cls[(((b << 6) + s) << 1) + 1];
        const int slot = ck - (start_s >> CSHIFT);            // 0..NSLOT-1
        *(float4*)&partials[((size_t)((b << 6) + s) * NSLOT + slot) * NH + (t << 2)] = s0;

        r = nb;
        ++s;
    }
}

// ---------------------------------------------------------------------------
// Kernel B: finalize -> X (bf16, 2048 x 1536): sum slots, mean | tab gather
// ---------------------------------------------------------------------------
__global__ __launch_bounds__(192) void finalize_kernel(const float* __restrict__ hs,
                                                       const float* __restrict__ partials,
                                                       const int* __restrict__ cls,
                                                       const int* __restrict__ tlen,
                                                       unsigned short* __restrict__ X) {
    const int seg = blockIdx.x;
    const int c   = threadIdx.x;
    const int b = seg >> 6, k = seg & 63;
    const int start = cls[seg * 2 + 1];
    int end = (k == NK - 1) ? NS : cls[seg * 2 + 3];
    const int tl = tlen[b];
    if (end > tl) end = tl;
    const int cnt = end - start;

    const int nslots = ((end - 1) >> CSHIFT) - (start >> CSHIFT) + 1;  // >=1 for cnt>=1

    float4 s = {0,0,0,0};
    for (int q = 0; q < nslots; ++q) {
        float4 p = *(const float4*)&partials[((size_t)seg * NSLOT + q) * NH + c * 4];
        ACC4(s, p)
    }
    const float inv = 1.0f / (float)cnt;

    const int tb = cls[seg * 2];
    float4 tv = *((const float4*)(hs + ((size_t)tb * NS + start) * NH) + c);

    ushort4 po, ta;
    po.x = f2bf(s.x * inv); po.y = f2bf(s.y * inv);
    po.z = f2bf(s.z * inv); po.w = f2bf(s.w * inv);
    ta.x = f2bf(tv.x); ta.y = f2bf(tv.y); ta.z = f2bf(tv.z); ta.w = f2bf(tv.w);

    unsigned short* xr = X + (size_t)seg * ND;
    *(ushort4*)&xr[c * 4]      = po;   // pooled half  [0,768)
    *(ushort4*)&xr[NH + c * 4] = ta;   // tab half     [768,1536)
}

// ---------------------------------------------------------------------------
// Kernel C: out = tanh(X @ Wc^T + b_dense + b_tab)   [R2-validated version]
// M=2048, N=768, K=1536. 64x64 block tile, 4 waves (2x2), BK=64,
// LDS double-buffer, ONE barrier/iter, prefetch distance 2 (named reg sets).
// Rows padded to 72 shorts (144B) -> 2-way max bank aliasing on ds_read_b128.
// ---------------------------------------------------------------------------
__global__ __launch_bounds__(256) void gemm_kernel(const unsigned short* __restrict__ X,
                                                   const unsigned short* __restrict__ Wc,
                                                   const float* __restrict__ bd,
                                                   const float* __restrict__ bt,
                                                   float* __restrict__ out) {
    __shared__ unsigned short Al[2][64 * 72];
    __shared__ unsigned short Bl[2][64 * 72];

    const int m0 = blockIdx.x * 64;
    const int n0 = blockIdx.y * 64;
    const int tid  = threadIdx.x;
    const int lane = tid & 63;
    const int wv   = tid >> 6;
    const int wr   = wv >> 1;          // wave row (0..1)
    const int wc   = wv & 1;           // wave col (0..1)
    const int lrow = lane & 15;
    const int hi   = lane >> 4;        // 0..3
    const int srow = tid >> 2;         // staging row 0..63
    const int sc   = tid & 3;          // staging chunk base (writes sc, sc+4)

    floatx4 acc[2][2] = {};

    const uint4* gA = (const uint4*)(X  + (size_t)(m0 + srow) * ND);
    const uint4* gB = (const uint4*)(Wc + (size_t)(n0 + srow) * ND);

    uint4 vA0[2], vA1[2], vB0[2], vB1[2];   // two named prefetch sets (rule #20)

    // prologue: tile0 -> set0 -> LDS buf0 ; tile1 -> set1 (held in regs)
    vA0[0] = gA[sc];     vA0[1] = gA[sc + 4];
    vB0[0] = gB[sc];     vB0[1] = gB[sc + 4];
    *(uint4*)&Al[0][srow * 72 + sc * 8]       = vA0[0];
    *(uint4*)&Al[0][srow * 72 + (sc + 4) * 8] = vA0[1];
    *(uint4*)&Bl[0][srow * 72 + sc * 8]       = vB0[0];
    *(uint4*)&Bl[0][srow * 72 + (sc + 4) * 8] = vB0[1];
    vA1[0] = gA[8 + sc]; vA1[1] = gA[8 + sc + 4];
    vB1[0] = gB[8 + sc]; vB1[1] = gB[8 + sc + 4];

#define GEMM_COMPUTE(RB)                                                             \
    _Pragma("unroll")                                                                \
    for (int ks = 0; ks < 2; ++ks) {                                                 \
        short8 a0 = *(const short8*)&Al[RB][(wr * 32 +      lrow) * 72 + ks * 32 + hi * 8]; \
        short8 a1 = *(const short8*)&Al[RB][(wr * 32 + 16 + lrow) * 72 + ks * 32 + hi * 8]; \
        short8 b0 = *(const short8*)&Bl[RB][(wc * 32 +      lrow) * 72 + ks * 32 + hi * 8]; \
        short8 b1 = *(const short8*)&Bl[RB][(wc * 32 + 16 + lrow) * 72 + ks * 32 + hi * 8]; \
        acc[0][0] = __builtin_amdgcn_mfma_f32_16x16x32_bf16(a0, b0, acc[0][0], 0, 0, 0);    \
        acc[0][1] = __builtin_amdgcn_mfma_f32_16x16x32_bf16(a0, b1, acc[0][1], 0, 0, 0);    \
        acc[1][0] = __builtin_amdgcn_mfma_f32_16x16x32_bf16(a1, b0, acc[1][0], 0, 0, 0);    \
        acc[1][1] = __builtin_amdgcn_mfma_f32_16x16x32_bf16(a1, b1, acc[1][1], 0, 0, 0);    \
    }

// iter kt (parity P): sync; prefetch tile kt+2 -> set P; compute buf P;
// store set (P^1), which holds tile kt+1, -> buf (P^1)
#define GEMM_ITER(kt, VA_L, VB_L, VA_S, VB_S, P)                                     \
    {                                                                                \
        __syncthreads();                                                             \
        if ((kt) + 2 < KT_TILES) {                                                   \
            VA_L[0] = gA[((kt) + 2) * 8 + sc]; VA_L[1] = gA[((kt) + 2) * 8 + sc + 4];\
            VB_L[0] = gB[((kt) + 2) * 8 + sc]; VB_L[1] = gB[((kt) + 2) * 8 + sc + 4];\
        }                                                                            \
        GEMM_COMPUTE(P)                                                              \
        if ((kt) + 1 < KT_TILES) {                                                   \
            *(uint4*)&Al[P ^ 1][srow * 72 + sc * 8]       = VA_S[0];                 \
            *(uint4*)&Al[P ^ 1][srow * 72 + (sc + 4) * 8] = VA_S[1];                 \
            *(uint4*)&Bl[P ^ 1][srow * 72 + sc * 8]       = VB_S[0];                 \
            *(uint4*)&Bl[P ^ 1][srow * 72 + (sc + 4) * 8] = VB_S[1];                 \
        }                                                                            \
    }

    for (int kt = 0; kt < KT_TILES; kt += 2) {
        GEMM_ITER(kt,     vA0, vB0, vA1, vB1, 0)
        GEMM_ITER(kt + 1, vA1, vB1, vA0, vB0, 1)
    }
#undef GEMM_ITER
#undef GEMM_COMPUTE

    // Epilogue: C/D layout col = lane&15, row = (lane>>4)*4 + reg  [HW-verified]
    for (int mi = 0; mi < 2; ++mi) {
        for (int ni = 0; ni < 2; ++ni) {
            int col  = n0 + wc * 32 + ni * 16 + lrow;
            float bias = bd[col] + bt[col];
            int rowb = m0 + wr * 32 + mi * 16 + hi * 4;
            #pragma unroll
            for (int j = 0; j < 4; ++j) {
                out[(size_t)(rowb + j) * NH + col] = tanhf(acc[mi][ni][j] + bias);
            }
        }
    }
}

// ---------------------------------------------------------------------------
extern "C" void kernel_launch(void* const* d_in, const int* in_sizes, int n_in,
                              void* d_out, int out_size, void* d_ws, size_t ws_size,
                              hipStream_t stream) {
    const float* hs  = (const float*)d_in[0];   // hidden_states (B,S,H) f32
    const float* Wd  = (const float*)d_in[1];   // W_dense (H,H)
    const float* bd  = (const float*)d_in[2];   // b_dense (H,)
    const float* Wt  = (const float*)d_in[3];   // W_tab (H,H)
    const float* bt  = (const float*)d_in[4];   // b_tab (H,)
    const int*   cls = (const int*)d_in[5];     // cls_indexes (B*K, 2) as int32
    const int*   tl  = (const int*)d_in[6];     // table_length (B,) as int32
    float* out = (float*)d_out;

    // ws layout: [partials f32 2048*65*768 = 409 MB] [Wc bf16] [X bf16]
    float*          partials = (float*)d_ws;
    unsigned short* Wc = (unsigned short*)(partials + (size_t)NM * NSLOT * NH);
    unsigned short* X  = Wc + (size_t)NH * ND;

    // uniform-chunk partial sums + fused weight convert
    pool_chunk_kernel<<<dim3(PBLOCKS + WCONV_BLOCKS), 192, 0, stream>>>(
        hs, cls, tl, partials, Wd, Wt, Wc);
    // finalize: combine slots, mean, tab gather, pack X (bf16)
    finalize_kernel<<<dim3(NM), 192, 0, stream>>>(hs, partials, cls, tl, X);
    // fused GEMM + bias + tanh (BK=64, one barrier/iter, double-buffered)
    gemm_kernel<<<dim3(NM / 64, NH / 64), 256, 0, stream>>>(X, Wc, bd, bt, out);
}

// Round 12
// 108.713 us; speedup vs baseline: 1.4405x; 1.4405x over previous
//
#include <hip/hip_runtime.h>
#include <hip/hip_bf16.h>

// Problem constants (BertMultiPooler: B=32, S=4096, H=768, K=64)
#define NB 32
#define NS 4096
#define NH 768
#define NK 64
#define NM (NB * NK)   // 2048 output rows
#define ND (2 * NH)    // 1536 GEMM reduction dim

// pool geometry: uniform 64-row chunks
#define CSHIFT 6
#define CROWS 64                 // rows per chunk
#define BPB (NS / CROWS)         // 64 chunks per batch
#define PBLOCKS (NB * BPB)       // 2048 pool blocks
#define NSLOT (BPB + 1)          // 65 partial slots per segment
#define WCONV_BLOCKS 384         // appended blocks for weight convert

typedef short short8 __attribute__((ext_vector_type(8)));
typedef float floatx4 __attribute__((ext_vector_type(4)));

__device__ __forceinline__ unsigned short f2bf(float f) {
    union { float f; unsigned u; } v; v.f = f;
    unsigned r = v.u + 0x7FFFu + ((v.u >> 16) & 1u);   // RNE to bf16
    return (unsigned short)(r >> 16);
}

// non-temporal float4 load via clang vector type (builtin rejects HIP structs).
// hs stream has zero reuse -> NT keeps partials/Wc/X resident in L2/L3.
// A/B evidence: R10 (NT) 144.3 vs R11 (plain) 156.6 with identical rest.
__device__ __forceinline__ floatx4 ntld(const float4* p) {
    return __builtin_nontemporal_load((const floatx4*)p);
}

#define ACC4(s, p) { s.x += p.x; s.y += p.y; s.z += p.z; s.w += p.w; }
#define ACCV(s, p) { s.x += p[0]; s.y += p[1]; s.z += p[2]; s.w += p[3]; }

// ---------------------------------------------------------------------------
// Kernel A: uniform-chunk segment partial sums + fused weight convert.
// Blocks [0,2048): one 64-row chunk (192 KB contiguous, uniform) per block.
// 192 threads; thread t owns cols 4t..4t+3. 8-deep register ping-pong.
// Per segment-run inside the chunk, flush one dense f32 partial slot:
//   partials[(seg*NSLOT + (chunk - seg_start_chunk))*NH + col]
// Blocks [2048, 2432): bf16 weight convert Wc = [W_dense | W_tab] rows.
// ---------------------------------------------------------------------------
__global__ __launch_bounds__(192) void pool_chunk_kernel(const float* __restrict__ hs,
                                                         const int* __restrict__ cls,
                                                         const int* __restrict__ tlen,
                                                         float* __restrict__ partials,
                                                         const float* __restrict__ Wd,
                                                         const float* __restrict__ Wt,
                                                         unsigned short* __restrict__ Wc) {
    const int bi = blockIdx.x;
    const int t  = threadIdx.x;          // 0..191

    if (bi >= PBLOCKS) {                 // ---- wconv part ----
        const int wb = bi - PBLOCKS;     // 0..383
        #pragma unroll
        for (int j = 0; j < 4; ++j) {
            int i = wb * 768 + j * 192 + t;      // float4 index, < NH*ND/4
            int e = i * 4;
            int n = e / ND;
            int k = e % ND;
            float4 v = (k < NH) ? *(const float4*)&Wd[n * NH + k]
                                : *(const float4*)&Wt[n * NH + (k - NH)];
            ushort4 o;
            o.x = f2bf(v.x); o.y = f2bf(v.y); o.z = f2bf(v.z); o.w = f2bf(v.w);
            *(ushort4*)&Wc[e] = o;
        }
        return;
    }

    // ---- pooling chunk ----
    const int b  = bi >> CSHIFT;         // batch (64 chunks per batch)
    const int ck = bi & (BPB - 1);       // chunk index within batch
    const int r0 = ck << CSHIFT;
    const int tl = tlen[b];
    int r_end = r0 + CROWS;
    if (r_end > tl) r_end = tl;
    if (r0 >= r_end) return;

    // s = upper_bound(pos, r0) - 1 over pos[k] = cls[((b<<6)+k)*2+1]
    int lo = 0, hb = NK;
    while (lo < hb) {
        int mid = (lo + hb) >> 1;
        int p = cls[(((b << 6) + mid) << 1) + 1];
        if (p <= r0) lo = mid + 1; else hb = mid;
    }
    int s = lo - 1;
    int r = r0;
    if (s < 0) {                         // rows before first boundary: invalid
        int p0 = cls[((b << 6) << 1) + 1];
        r = (p0 < r_end) ? p0 : r_end;
        s = 0;
        if (r >= r_end) return;
    }

    const float4* base = (const float4*)(hs + (size_t)b * NS * NH) + t;

    while (r < r_end) {
        int nb = r_end;
        if (s + 1 < NK) {
            int p = cls[(((b << 6) + s + 1) << 1) + 1];
            if (p < nb) nb = p;
        }
        const int n = nb - r;
        const float4* p4 = base + (size_t)r * (NH / 4);

        float4 s0 = {0,0,0,0}, s1 = {0,0,0,0}, s2 = {0,0,0,0}, s3 = {0,0,0,0};
        int i = 0;
        if (n >= 8) {
            floatx4 p0 = ntld(&p4[0*(NH/4)]), p1 = ntld(&p4[1*(NH/4)]),
                    p2 = ntld(&p4[2*(NH/4)]), p3 = ntld(&p4[3*(NH/4)]);
            floatx4 a4 = ntld(&p4[4*(NH/4)]), a5 = ntld(&p4[5*(NH/4)]),
                    a6 = ntld(&p4[6*(NH/4)]), a7 = ntld(&p4[7*(NH/4)]);
            for (i = 8; i + 8 <= n; i += 8) {
                floatx4 q0 = ntld(&p4[(size_t)(i+0) * (NH/4)]);
                floatx4 q1 = ntld(&p4[(size_t)(i+1) * (NH/4)]);
                floatx4 q2 = ntld(&p4[(size_t)(i+2) * (NH/4)]);
                floatx4 q3 = ntld(&p4[(size_t)(i+3) * (NH/4)]);
                floatx4 q4 = ntld(&p4[(size_t)(i+4) * (NH/4)]);
                floatx4 q5 = ntld(&p4[(size_t)(i+5) * (NH/4)]);
                floatx4 q6 = ntld(&p4[(size_t)(i+6) * (NH/4)]);
                floatx4 q7 = ntld(&p4[(size_t)(i+7) * (NH/4)]);
                ACCV(s0, p0) ACCV(s1, p1) ACCV(s2, p2) ACCV(s3, p3)
                ACCV(s0, a4) ACCV(s1, a5) ACCV(s2, a6) ACCV(s3, a7)
                p0 = q0; p1 = q1; p2 = q2; p3 = q3;
                a4 = q4; a5 = q5; a6 = q6; a7 = q7;
            }
            ACCV(s0, p0) ACCV(s1, p1) ACCV(s2, p2) ACCV(s3, p3)
            ACCV(s0, a4) ACCV(s1, a5) ACCV(s2, a6) ACCV(s3, a7)
        }
        for (; i < n; ++i) {
            floatx4 v = ntld(&p4[(size_t)i * (NH/4)]);
            ACCV(s0, v)
        }
        ACC4(s0, s1) ACC4(s2, s3) ACC4(s0, s2)

        const int start_s = cls[(((b << 6) + s) << 1) + 1];
        const int slot = ck - (start_s >> CSHIFT);            // 0..NSLOT-1
        *(float4*)&partials[((size_t)((b << 6) + s) * NSLOT + slot) * NH + (t << 2)] = s0;

        r = nb;
        ++s;
    }
}

// ---------------------------------------------------------------------------
// Kernel B: finalize -> X (bf16, 2048 x 1536): sum slots, mean | tab gather
// ---------------------------------------------------------------------------
__global__ __launch_bounds__(192) void finalize_kernel(const float* __restrict__ hs,
                                                       const float* __restrict__ partials,
                                                       const int* __restrict__ cls,
                                                       const int* __restrict__ tlen,
                                                       unsigned short* __restrict__ X) {
    const int seg = blockIdx.x;
    const int c   = threadIdx.x;
    const int b = seg >> 6, k = seg & 63;
    const int start = cls[seg * 2 + 1];
    int end = (k == NK - 1) ? NS : cls[seg * 2 + 3];
    const int tl = tlen[b];
    if (end > tl) end = tl;
    const int cnt = end - start;

    const int nslots = ((end - 1) >> CSHIFT) - (start >> CSHIFT) + 1;  // >=1 for cnt>=1

    float4 s = {0,0,0,0};
    for (int q = 0; q < nslots; ++q) {
        float4 p = *(const float4*)&partials[((size_t)seg * NSLOT + q) * NH + c * 4];
        ACC4(s, p)
    }
    const float inv = 1.0f / (float)cnt;

    const int tb = cls[seg * 2];
    float4 tv = *((const float4*)(hs + ((size_t)tb * NS + start) * NH) + c);

    ushort4 po, ta;
    po.x = f2bf(s.x * inv); po.y = f2bf(s.y * inv);
    po.z = f2bf(s.z * inv); po.w = f2bf(s.w * inv);
    ta.x = f2bf(tv.x); ta.y = f2bf(tv.y); ta.z = f2bf(tv.z); ta.w = f2bf(tv.w);

    unsigned short* xr = X + (size_t)seg * ND;
    *(ushort4*)&xr[c * 4]      = po;   // pooled half  [0,768)
    *(ushort4*)&xr[NH + c * 4] = ta;   // tab half     [768,1536)
}

// ---------------------------------------------------------------------------
// Kernel C: out = tanh(X @ Wc^T + b_dense + b_tab)   [R8-proven BK=32 version]
// M=2048, N=768, K=1536, bf16 MFMA 16x16x32, f32 accumulate.
// Block tile 64x64 (4 waves, 2x2), BK=32, 2 barriers/iter, prefetch dist 1.
// A/B evidence: R8 (this gemm) 121.7 vs R11 (BK=64 dbuf) 156.6, rest identical.
// ---------------------------------------------------------------------------
__global__ __launch_bounds__(256) void gemm_kernel(const unsigned short* __restrict__ X,
                                                   const unsigned short* __restrict__ Wc,
                                                   const float* __restrict__ bd,
                                                   const float* __restrict__ bt,
                                                   float* __restrict__ out) {
    __shared__ unsigned short Al[64 * 40];
    __shared__ unsigned short Bl[64 * 40];

    const int m0 = blockIdx.x * 64;
    const int n0 = blockIdx.y * 64;
    const int tid  = threadIdx.x;
    const int lane = tid & 63;
    const int wv   = tid >> 6;
    const int wr   = wv >> 1;          // wave row (0..1)
    const int wc   = wv & 1;           // wave col (0..1)
    const int lrow = lane & 15;
    const int hi   = lane >> 4;        // 0..3
    const int srow   = tid >> 2;       // staging row 0..63
    const int schunk = tid & 3;        // staging 16B chunk 0..3

    floatx4 acc[2][2] = {};

    const uint4* gA = (const uint4*)(X  + (size_t)(m0 + srow) * ND) + schunk;
    const uint4* gB = (const uint4*)(Wc + (size_t)(n0 + srow) * ND) + schunk;

    uint4 va = gA[0];
    uint4 vb = gB[0];

    const int KT = ND / 32;            // 48
    for (int kt = 0; kt < KT; ++kt) {
        __syncthreads();               // previous iter's ds_reads done
        *(uint4*)&Al[srow * 40 + schunk * 8] = va;
        *(uint4*)&Bl[srow * 40 + schunk * 8] = vb;
        __syncthreads();

        if (kt + 1 < KT) {             // prefetch next tile while MFMAs run
            va = gA[(kt + 1) * 4];
            vb = gB[(kt + 1) * 4];
        }

        short8 a0 = *(const short8*)&Al[(wr * 32 +      lrow) * 40 + hi * 8];
        short8 a1 = *(const short8*)&Al[(wr * 32 + 16 + lrow) * 40 + hi * 8];
        short8 b0 = *(const short8*)&Bl[(wc * 32 +      lrow) * 40 + hi * 8];
        short8 b1 = *(const short8*)&Bl[(wc * 32 + 16 + lrow) * 40 + hi * 8];

        acc[0][0] = __builtin_amdgcn_mfma_f32_16x16x32_bf16(a0, b0, acc[0][0], 0, 0, 0);
        acc[0][1] = __builtin_amdgcn_mfma_f32_16x16x32_bf16(a0, b1, acc[0][1], 0, 0, 0);
        acc[1][0] = __builtin_amdgcn_mfma_f32_16x16x32_bf16(a1, b0, acc[1][0], 0, 0, 0);
        acc[1][1] = __builtin_amdgcn_mfma_f32_16x16x32_bf16(a1, b1, acc[1][1], 0, 0, 0);
    }

    // Epilogue: C/D layout col = lane&15, row = (lane>>4)*4 + reg  [HW-verified]
    for (int mi = 0; mi < 2; ++mi) {
        for (int ni = 0; ni < 2; ++ni) {
            int col  = n0 + wc * 32 + ni * 16 + lrow;
            float bias = bd[col] + bt[col];
            int rowb = m0 + wr * 32 + mi * 16 + hi * 4;
            #pragma unroll
            for (int j = 0; j < 4; ++j) {
                out[(size_t)(rowb + j) * NH + col] = tanhf(acc[mi][ni][j] + bias);
            }
        }
    }
}

// ---------------------------------------------------------------------------
extern "C" void kernel_launch(void* const* d_in, const int* in_sizes, int n_in,
                              void* d_out, int out_size, void* d_ws, size_t ws_size,
                              hipStream_t stream) {
    const float* hs  = (const float*)d_in[0];   // hidden_states (B,S,H) f32
    const float* Wd  = (const float*)d_in[1];   // W_dense (H,H)
    const float* bd  = (const float*)d_in[2];   // b_dense (H,)
    const float* Wt  = (const float*)d_in[3];   // W_tab (H,H)
    const float* bt  = (const float*)d_in[4];   // b_tab (H,)
    const int*   cls = (const int*)d_in[5];     // cls_indexes (B*K, 2) as int32
    const int*   tl  = (const int*)d_in[6];     // table_length (B,) as int32
    float* out = (float*)d_out;

    // ws layout: [partials f32 2048*65*768 = 409 MB] [Wc bf16] [X bf16]
    float*          partials = (float*)d_ws;
    unsigned short* Wc = (unsigned short*)(partials + (size_t)NM * NSLOT * NH);
    unsigned short* X  = Wc + (size_t)NH * ND;

    // uniform-chunk partial sums (NT hs loads) + fused weight convert
    pool_chunk_kernel<<<dim3(PBLOCKS + WCONV_BLOCKS), 192, 0, stream>>>(
        hs, cls, tl, partials, Wd, Wt, Wc);
    // finalize: combine slots, mean, tab gather, pack X (bf16)
    finalize_kernel<<<dim3(NM), 192, 0, stream>>>(hs, partials, cls, tl, X);
    // fused GEMM + bias + tanh (BK=32, 2 barriers/iter — R8-proven)
    gemm_kernel<<<dim3(NM / 64, NH / 64), 256, 0, stream>>>(X, Wc, bd, bt, out);
}